// Round 8
// baseline (1128.396 us; speedup 1.0000x reference)
//
#include <hip/hip_runtime.h>
#include <hip/hip_bf16.h>

// LightGCN K=3 propagation on MI355X.
// R5 third resubmit (GPU-acquisition timeouts; never ran): two-phase bucketed
// CSR build replaces the random-scatter counting sort.
//   P1: append edge into its 64-row bucket's final CSR span (atomic cursor per
//       bucket) -> write amplification ~1 (was 8x, WRITE_SIZE 204MB).
//   P2: one block per bucket: span -> LDS, per-row count + wave scan, rewrite
//       span sorted by row (coalesced, in-place; reads all precede writes).
// SpMM unchanged (gather-BW-bound at ~6.5 TB/s effective).

#define DD 64            // feature dim
#define SCAN_BLOCK 256
#define SCAN_ITEMS 2
#define SCAN_CHUNK (SCAN_BLOCK * SCAN_ITEMS)   // 512 elems per block
#define BSHIFT 6                                // 64 rows per bucket
#define BROWS (1 << BSHIFT)
#define BCAP 6144                               // entries per bucket (mean ~2112)

__global__ void count_kernel(const int* __restrict__ rows, int* __restrict__ cnt, int E) {
    int i = blockIdx.x * blockDim.x + threadIdx.x;
    int stride = gridDim.x * blockDim.x;
    for (; i < E; i += stride) atomicAdd(&cnt[rows[i]], 1);
}

__global__ void factor_kernel(const int* __restrict__ cnt,
                              float* __restrict__ a_fac,
                              float* __restrict__ b_fac, int n) {
    int i = blockIdx.x * blockDim.x + threadIdx.x;
    if (i >= n) return;
    float degf = (float)(cnt[i] + 1);            // +1 self loop
    float inv_deg = 1.0f / (degf + 1e-8f);
    float deg2 = degf * inv_deg;                 // == segment_sum of inv_deg copies
    float inv_sqrt = 1.0f / sqrtf(deg2 + 1e-8f);
    a_fac[i] = inv_sqrt * inv_deg;               // matches (inv_sqrt[row] * w) grouping
    b_fac[i] = inv_sqrt;
}

// ---- 3-phase device-wide exclusive scan of (cnt[i]+1) ----
__global__ void scan_phase1(const int* __restrict__ cnt,
                            int* __restrict__ blk_sum, int n) {
    __shared__ int sh[SCAN_BLOCK];
    int b = blockIdx.x, tid = threadIdx.x;
    int base = b * SCAN_CHUNK + tid * SCAN_ITEMS;
    int s = 0;
#pragma unroll
    for (int k = 0; k < SCAN_ITEMS; ++k) {
        int i = base + k;
        if (i < n) s += cnt[i] + 1;
    }
    sh[tid] = s;
    __syncthreads();
    for (int off = SCAN_BLOCK / 2; off > 0; off >>= 1) {
        if (tid < off) sh[tid] += sh[tid + off];
        __syncthreads();
    }
    if (tid == 0) blk_sum[b] = sh[0];
}

__global__ void scan_phase2(const int* __restrict__ blk_sum,
                            int* __restrict__ blk_off, int nb) {
    __shared__ int sh[256];
    int tid = threadIdx.x;
    int m = (nb + 255) >> 8;                 // partials per thread
    int base = tid * m;
    int s = 0;
    for (int k = 0; k < m; ++k) {
        int i = base + k;
        if (i < nb) s += blk_sum[i];
    }
    sh[tid] = s;
    __syncthreads();
    for (int off = 1; off < 256; off <<= 1) {
        int v = sh[tid];
        int add = (tid >= off) ? sh[tid - off] : 0;
        __syncthreads();
        sh[tid] = v + add;
        __syncthreads();
    }
    int excl = (tid == 0) ? 0 : sh[tid - 1];
    for (int k = 0; k < m; ++k) {
        int i = base + k;
        if (i < nb) {
            blk_off[i] = excl;
            excl += blk_sum[i];
        }
    }
}

__global__ void scan_phase3(const int* __restrict__ cnt,
                            const int* __restrict__ blk_off,
                            int* __restrict__ row_start, int n) {
    __shared__ int sh[SCAN_BLOCK];
    int b = blockIdx.x, tid = threadIdx.x;
    int base = b * SCAN_CHUNK + tid * SCAN_ITEMS;
    int loc[SCAN_ITEMS];
    int s = 0;
#pragma unroll
    for (int k = 0; k < SCAN_ITEMS; ++k) {
        int i = base + k;
        int v = (i < n) ? cnt[i] + 1 : 0;
        loc[k] = s;
        s += v;
    }
    sh[tid] = s;
    __syncthreads();
    for (int off = 1; off < SCAN_BLOCK; off <<= 1) {
        int v = sh[tid];
        int add = (tid >= off) ? sh[tid - off] : 0;
        __syncthreads();
        sh[tid] = v + add;
        __syncthreads();
    }
    int thr_off = blk_off[b] + ((tid == 0) ? 0 : sh[tid - 1]);
#pragma unroll
    for (int k = 0; k < SCAN_ITEMS; ++k) {
        int i = base + k;
        if (i < n) {
            int v = thr_off + loc[k];
            row_start[i] = v;
            if (i == n - 1) row_start[n] = v + cnt[i] + 1;
        }
    }
}

__global__ void bucket_init_kernel(const int* __restrict__ row_start,
                                   int* __restrict__ bucket_cur, int nbk) {
    int b = blockIdx.x * blockDim.x + threadIdx.x;
    if (b < nbk) bucket_cur[b] = row_start[b << BSHIFT];
}

// P1: append edge into its bucket's CSR span. Entry packs
//   hi32 = w bits, lo32 = (r_local<<26) | c   (c < 2^17 here, r_local < 64)
__global__ void __launch_bounds__(256)
scatter_bucket_kernel(const int* __restrict__ ei,      // [2*E] rows then cols
                      const float* __restrict__ drop,  // [E+n]
                      const float* __restrict__ a_fac,
                      const float* __restrict__ b_fac,
                      int* __restrict__ bucket_cur,
                      unsigned long long* __restrict__ csr_ew,
                      int E, int n) {
    int i = blockIdx.x * blockDim.x + threadIdx.x;
    if (i >= E + n) return;
    int r, c;
    if (i < E) { r = ei[i]; c = ei[E + i]; }
    else       { r = i - E; c = r; }            // self loop
    float w = (a_fac[r] * b_fac[c]) * drop[i];
    int pos = atomicAdd(&bucket_cur[r >> BSHIFT], 1);
    unsigned int lo = ((unsigned int)(r & (BROWS - 1)) << 26) | (unsigned int)c;
    csr_ew[pos] = ((unsigned long long)__float_as_uint(w) << 32) | lo;
}

// P2: sort a bucket's span by row, in place via LDS staging.
__global__ void __launch_bounds__(256)
bucket_sort_kernel(const int* __restrict__ row_start,
                   unsigned long long* __restrict__ csr_ew, int n) {
    __shared__ unsigned long long ent[BCAP];
    __shared__ int cnt_sh[BROWS];
    __shared__ int cur[BROWS];
    int b = blockIdx.x, tid = threadIdx.x;
    int r0 = b << BSHIFT;
    int rows = n - r0; if (rows > BROWS) rows = BROWS;
    int s = row_start[r0];
    int e = row_start[r0 + rows];
    int m = e - s;                               // <= BCAP by construction
    if (tid < BROWS) cnt_sh[tid] = 0;
    __syncthreads();
    for (int i = tid; i < m; i += 256) {
        unsigned long long v = csr_ew[s + i];
        ent[i] = v;
        int rl = ((unsigned int)v >> 26) & (BROWS - 1);
        atomicAdd(&cnt_sh[rl], 1);
    }
    __syncthreads();
    if (tid < BROWS) {
        int v = cnt_sh[tid];
        int incl = v;
        for (int off = 1; off < BROWS; off <<= 1) {
            int u = __shfl_up(incl, off, BROWS);
            if (tid >= off) incl += u;
        }
        cur[tid] = incl - v;                     // exclusive scan
    }
    __syncthreads();
    for (int i = tid; i < m; i += 256) {
        unsigned long long v = ent[i];
        unsigned int lo = (unsigned int)v;
        int rl = (lo >> 26) & (BROWS - 1);
        int pos = atomicAdd(&cur[rl], 1);
        csr_ew[s + pos] = (v & 0xFFFFFFFF00000000ull) |
                          (unsigned long long)(lo & 0x03FFFFFFu);
    }
}

// one wave (64 lanes) per destination row; lane = feature dim.
// Edge loop unrolled x8: 8 independent gathers in flight per wave.
__global__ void __launch_bounds__(256)
spmm_kernel(const int* __restrict__ row_start,
            const unsigned long long* __restrict__ csr_ew,
            const float* __restrict__ h_in,
            float* __restrict__ h_out,
            const float* __restrict__ acc_in,
            float* __restrict__ acc_out,
            float scale, int n) {
    int wave_global = (blockIdx.x * blockDim.x + threadIdx.x) >> 6;
    int lane = threadIdx.x & 63;
    if (wave_global >= n) return;
    int beg = row_start[wave_global];
    int end = row_start[wave_global + 1];

    float s0 = 0.f, s1 = 0.f, s2 = 0.f, s3 = 0.f;
    float s4 = 0.f, s5 = 0.f, s6 = 0.f, s7 = 0.f;

    int j = beg;
    int main_end = beg + ((end - beg) & ~7);
    for (; j < main_end; j += 8) {
        unsigned long long e0 = csr_ew[j + 0];
        unsigned long long e1 = csr_ew[j + 1];
        unsigned long long e2 = csr_ew[j + 2];
        unsigned long long e3 = csr_ew[j + 3];
        unsigned long long e4 = csr_ew[j + 4];
        unsigned long long e5 = csr_ew[j + 5];
        unsigned long long e6 = csr_ew[j + 6];
        unsigned long long e7 = csr_ew[j + 7];
        int c0 = (int)(unsigned int)e0; float w0 = __uint_as_float((unsigned int)(e0 >> 32));
        int c1 = (int)(unsigned int)e1; float w1 = __uint_as_float((unsigned int)(e1 >> 32));
        int c2 = (int)(unsigned int)e2; float w2 = __uint_as_float((unsigned int)(e2 >> 32));
        int c3 = (int)(unsigned int)e3; float w3 = __uint_as_float((unsigned int)(e3 >> 32));
        int c4 = (int)(unsigned int)e4; float w4 = __uint_as_float((unsigned int)(e4 >> 32));
        int c5 = (int)(unsigned int)e5; float w5 = __uint_as_float((unsigned int)(e5 >> 32));
        int c6 = (int)(unsigned int)e6; float w6 = __uint_as_float((unsigned int)(e6 >> 32));
        int c7 = (int)(unsigned int)e7; float w7 = __uint_as_float((unsigned int)(e7 >> 32));
        float v0 = h_in[c0 * DD + lane];
        float v1 = h_in[c1 * DD + lane];
        float v2 = h_in[c2 * DD + lane];
        float v3 = h_in[c3 * DD + lane];
        float v4 = h_in[c4 * DD + lane];
        float v5 = h_in[c5 * DD + lane];
        float v6 = h_in[c6 * DD + lane];
        float v7 = h_in[c7 * DD + lane];
        s0 += w0 * v0; s1 += w1 * v1; s2 += w2 * v2; s3 += w3 * v3;
        s4 += w4 * v4; s5 += w5 * v5; s6 += w6 * v6; s7 += w7 * v7;
    }
    for (; j < end; ++j) {
        unsigned long long e = csr_ew[j];
        int c = (int)(unsigned int)e;
        float w = __uint_as_float((unsigned int)(e >> 32));
        s0 += w * h_in[c * DD + lane];
    }
    float sum = ((s0 + s1) + (s2 + s3)) + ((s4 + s5) + (s6 + s7));

    int idx = wave_global * DD + lane;
    h_out[idx] = sum;
    acc_out[idx] = (acc_in[idx] + sum) * scale;
}

extern "C" void kernel_launch(void* const* d_in, const int* in_sizes, int n_in,
                              void* d_out, int out_size, void* d_ws, size_t ws_size,
                              hipStream_t stream) {
    const float* x    = (const float*)d_in[0];
    const int*   ei   = (const int*)d_in[1];
    const float* drop = (const float*)d_in[2];
    float* out = (float*)d_out;

    const int N = in_sizes[0] / DD;      // 100000
    const int E = in_sizes[1] / 2;       // 3200000
    const int TOT = E + N;
    const int NB  = (N + SCAN_CHUNK - 1) / SCAN_CHUNK;   // scan blocks (~196)
    const int NBK = (N + BROWS - 1) / BROWS;             // buckets (1563)

    // workspace carve (256B aligned)
    char* p = (char*)d_ws;
    auto alloc = [&](size_t bytes) -> void* {
        void* r = (void*)p;
        p += (bytes + 255) & ~(size_t)255;
        return r;
    };
    int*   deg_cnt    = (int*)  alloc((size_t)N * 4);
    int*   row_start  = (int*)  alloc((size_t)(N + 1) * 4);
    float* a_fac      = (float*)alloc((size_t)N * 4);
    float* b_fac      = (float*)alloc((size_t)N * 4);
    int*   blk_sum    = (int*)  alloc((size_t)NB * 4);
    int*   blk_off    = (int*)  alloc((size_t)NB * 4);
    int*   bucket_cur = (int*)  alloc((size_t)NBK * 4);
    unsigned long long* csr_ew = (unsigned long long*)alloc((size_t)TOT * 8);
    float* h_a        = (float*)alloc((size_t)N * DD * 4);
    float* h_b        = (float*)alloc((size_t)N * DD * 4);

    hipMemsetAsync(deg_cnt, 0, (size_t)N * 4, stream);

    count_kernel<<<2048, 256, 0, stream>>>(ei, deg_cnt, E);
    factor_kernel<<<(N + 255) / 256, 256, 0, stream>>>(deg_cnt, a_fac, b_fac, N);
    scan_phase1<<<NB, SCAN_BLOCK, 0, stream>>>(deg_cnt, blk_sum, N);
    scan_phase2<<<1, 256, 0, stream>>>(blk_sum, blk_off, NB);
    scan_phase3<<<NB, SCAN_BLOCK, 0, stream>>>(deg_cnt, blk_off, row_start, N);
    bucket_init_kernel<<<(NBK + 255) / 256, 256, 0, stream>>>(row_start, bucket_cur, NBK);
    scatter_bucket_kernel<<<(TOT + 255) / 256, 256, 0, stream>>>(
        ei, drop, a_fac, b_fac, bucket_cur, csr_ew, E, N);
    bucket_sort_kernel<<<NBK, 256, 0, stream>>>(row_start, csr_ew, N);

    const int rows_per_block = 256 / 64;
    const int spmm_grid = (N + rows_per_block - 1) / rows_per_block;

    // hop 1: h_a = A x ; out = x + h_a
    spmm_kernel<<<spmm_grid, 256, 0, stream>>>(row_start, csr_ew,
                                               x, h_a, x, out, 1.0f, N);
    // hop 2: h_b = A h_a ; out += h_b
    spmm_kernel<<<spmm_grid, 256, 0, stream>>>(row_start, csr_ew,
                                               h_a, h_b, out, out, 1.0f, N);
    // hop 3: h_a = A h_b ; out = (out + h_a) * 0.25
    spmm_kernel<<<spmm_grid, 256, 0, stream>>>(row_start, csr_ew,
                                               h_b, h_a, out, out, 0.25f, N);
}